// Round 3
// baseline (403.742 us; speedup 1.0000x reference)
//
#include <hip/hip_runtime.h>
#include <math.h>

#define D_MODEL 2048
#define NH 16
#define DH 128
#define SEQ 2048
#define NBH 32  // batch * heads

typedef unsigned short u16;
typedef unsigned int u32;
typedef __attribute__((ext_vector_type(8))) short short8;
typedef __attribute__((ext_vector_type(4))) float floatx4;
typedef __attribute__((ext_vector_type(2))) unsigned int uint2v;
typedef __attribute__((ext_vector_type(4))) unsigned short ushort4v;

__device__ __forceinline__ u16 f2bf(float f) {
  u32 u = __builtin_bit_cast(u32, f);
  return (u16)((u + 0x8000u) >> 16);
}
__device__ __forceinline__ float bf2f(u16 h) {
  return __builtin_bit_cast(float, (u32)h << 16);
}

// async global->LDS, 16B per lane. LDS dest = wave-uniform base + lane*16.
__device__ __forceinline__ void async_load16(const u16* g, u16* l) {
  __builtin_amdgcn_global_load_lds(
      (const __attribute__((address_space(1))) void*)g,
      (__attribute__((address_space(3))) void*)l, 16, 0, 0);
}

// ---------------------------------------------------------------------------
// f32 -> bf16 elementwise convert. n multiple of 2048. 8 elems/thread.
// ---------------------------------------------------------------------------
__global__ void cvt_kernel(const float* __restrict__ src, u16* __restrict__ dst,
                           int n) {
  const int i = (blockIdx.x * 256 + threadIdx.x) * 8;
  if (i >= n) return;
  const floatx4 a = *(const floatx4*)(src + i);
  const floatx4 b = *(const floatx4*)(src + i + 4);
  short8 h;
  h[0] = (short)f2bf(a[0]); h[1] = (short)f2bf(a[1]);
  h[2] = (short)f2bf(a[2]); h[3] = (short)f2bf(a[3]);
  h[4] = (short)f2bf(b[0]); h[5] = (short)f2bf(b[1]);
  h[6] = (short)f2bf(b[2]); h[7] = (short)f2bf(b[3]);
  *(short8*)(dst + i) = h;
}

// Merged upfront conversions: x (4096 blocks), Wq/Wk/Wv (2048 each), plus
// 128 blocks generating the RoPE cos/sin table (SEQ x 64 float2 = 1 MB).
__global__ void cvt4_kernel(const float* __restrict__ x,
                            const float* __restrict__ wq,
                            const float* __restrict__ wk,
                            const float* __restrict__ wv, u16* __restrict__ xb,
                            u16* __restrict__ wqb, u16* __restrict__ wkb,
                            u16* __restrict__ wvb, float* __restrict__ rtab) {
  const int blk = blockIdx.x;
  if (blk >= 10240) {
    // RoPE table: entry e = (s, p): rtab[2e] = cos(s*freq_p), rtab[2e+1]=sin
    const int e0 = ((blk - 10240) * 256 + threadIdx.x) * 4;
#pragma unroll
    for (int e = e0; e < e0 + 4; ++e) {
      const int s = e >> 6, p = e & 63;
      const float freq = exp2f(-(float)p * (13.287712379549449f / 64.0f));
      float sn, cs;
      sincosf((float)s * freq, &sn, &cs);
      rtab[2 * e] = cs;
      rtab[2 * e + 1] = sn;
    }
    return;
  }
  const float* src;
  u16* dst;
  int base;
  if (blk < 4096) {
    src = x; dst = xb; base = blk;
  } else if (blk < 6144) {
    src = wq; dst = wqb; base = blk - 4096;
  } else if (blk < 8192) {
    src = wk; dst = wkb; base = blk - 6144;
  } else {
    src = wv; dst = wvb; base = blk - 8192;
  }
  const int i = (base * 256 + threadIdx.x) * 8;
  const floatx4 a = *(const floatx4*)(src + i);
  const floatx4 b = *(const floatx4*)(src + i + 4);
  short8 h;
  h[0] = (short)f2bf(a[0]); h[1] = (short)f2bf(a[1]);
  h[2] = (short)f2bf(a[2]); h[3] = (short)f2bf(a[3]);
  h[4] = (short)f2bf(b[0]); h[5] = (short)f2bf(b[1]);
  h[6] = (short)f2bf(b[2]); h[7] = (short)f2bf(b[3]);
  *(short8*)(dst + i) = h;
}

// ---------------------------------------------------------------------------
// bf16 GEMM. This round: 2-phase pipeline (T3-minimum) — double-buffered LDS,
// STAGE(t+1) issued BEFORE compute(t), one barrier per K-tile so staging
// latency hides under the 32-MFMA compute phase. Plus fused RoPE epilogue for
// Q/K (modes 0/1) via cos/sin table + shfl_xor(1) lane pairing.
// ---------------------------------------------------------------------------
__global__ __launch_bounds__(256, 2) void gemm_async(
    const u16* __restrict__ A, const u16* __restrict__ W0,
    const u16* __restrict__ W1, const u16* __restrict__ W2,
    const float* __restrict__ b0, const float* __restrict__ b1,
    const float* __restrict__ b2, void* __restrict__ C0, void* __restrict__ C1,
    void* __restrict__ C2, const float* __restrict__ rtab, const int qkv) {
  __shared__ u16 As[2][128 * 64];
  __shared__ u16 Bs[2][128 * 64];
  const int tid = threadIdx.x;
  const int wave = tid >> 6, lane = tid & 63;
  const int lr = lane & 15, lg = lane >> 4;
  const int m0 = blockIdx.y * 128;
  const int wm = (wave & 1) * 64, wn = (wave >> 1) * 64;

  int n0, mode;
  const u16* W;
  const float* bias;
  void* C;
  if (qkv) {
    const int which = blockIdx.x >> 4;
    n0 = (blockIdx.x & 15) * 128;
    W = which == 0 ? W0 : which == 1 ? W1 : W2;
    bias = which == 0 ? b0 : which == 1 ? b1 : b2;
    C = which == 0 ? C0 : which == 1 ? C1 : C2;
    mode = which;
  } else {
    n0 = blockIdx.x * 128;
    W = W0; bias = b0; C = C0; mode = 3;
  }

  floatx4 acc[4][4];
#pragma unroll
  for (int i = 0; i < 4; ++i)
#pragma unroll
    for (int j = 0; j < 4; ++j) {
      floatx4 z = {0.f, 0.f, 0.f, 0.f};
      acc[i][j] = z;
    }

#define STAGE_TILE(buf, kt)                                              \
  {                                                                      \
    _Pragma("unroll") for (int p = 0; p < 4; ++p) {                      \
      const int sIdx = p * 256 + tid;                                    \
      const int row = sIdx >> 3, c = sIdx & 7;                           \
      const int g = c ^ (row & 7);                                       \
      async_load16(A + (size_t)(m0 + row) * D_MODEL + (kt) + g * 8,      \
                   &As[buf][(p * 256 + wave * 64) * 8]);                 \
    }                                                                    \
    _Pragma("unroll") for (int p = 0; p < 4; ++p) {                      \
      const int sIdx = p * 256 + tid;                                    \
      const int row = sIdx >> 3, c = sIdx & 7;                           \
      const int g = c ^ (row & 7);                                       \
      async_load16(W + (size_t)(n0 + row) * D_MODEL + (kt) + g * 8,      \
                   &Bs[buf][(p * 256 + wave * 64) * 8]);                 \
    }                                                                    \
  }

  // prologue: stage tile 0 into buffer 0
  STAGE_TILE(0, 0);
  __syncthreads();

  int cur = 0;
  for (int kt = 0; kt < D_MODEL; kt += 64) {
    if (kt + 64 < D_MODEL) STAGE_TILE(cur ^ 1, kt + 64);
#pragma unroll
    for (int ks = 0; ks < 2; ++ks) {
      short8 af[4], bfr[4];
      const int ch = (ks * 4 + lg) ^ (lr & 7);
#pragma unroll
      for (int i = 0; i < 4; ++i)
        af[i] = *(const short8*)&As[cur][(wm + 16 * i + lr) * 64 + ch * 8];
#pragma unroll
      for (int j = 0; j < 4; ++j)
        bfr[j] = *(const short8*)&Bs[cur][(wn + 16 * j + lr) * 64 + ch * 8];
      __builtin_amdgcn_s_setprio(1);
#pragma unroll
      for (int i = 0; i < 4; ++i)
#pragma unroll
        for (int j = 0; j < 4; ++j)
          acc[i][j] = __builtin_amdgcn_mfma_f32_16x16x32_bf16(af[i], bfr[j],
                                                              acc[i][j], 0, 0, 0);
      __builtin_amdgcn_s_setprio(0);
    }
    __syncthreads();  // drains vmcnt (next tile landed) + protects buffers
    cur ^= 1;
  }
#undef STAGE_TILE

  float bj[4];
  int ncol[4];
#pragma unroll
  for (int j = 0; j < 4; ++j) {
    ncol[j] = n0 + wn + 16 * j + lr;
    bj[j] = bias[ncol[j]];
  }

  if (mode == 3) {
    float* Cf = (float*)C;
#pragma unroll
    for (int i = 0; i < 4; ++i)
#pragma unroll
      for (int r = 0; r < 4; ++r) {
        const int m = m0 + wm + 16 * i + lg * 4 + r;
#pragma unroll
        for (int j = 0; j < 4; ++j)
          Cf[(size_t)m * D_MODEL + ncol[j]] = acc[i][j][r] + bj[j];
      }
  } else if (mode == 2) {
    u16* Ch = (u16*)C;
#pragma unroll
    for (int i = 0; i < 4; ++i)
#pragma unroll
      for (int r = 0; r < 4; ++r) {
        const int m = m0 + wm + 16 * i + lg * 4 + r;
        const int b = m >> 11, s = m & (SEQ - 1);
#pragma unroll
        for (int j = 0; j < 4; ++j) {
          const int h = ncol[j] >> 7, d = ncol[j] & (DH - 1);
          Ch[((size_t)((b * NH + h) * DH + d)) * SEQ + s] =
              f2bf(acc[i][j][r] + bj[j]);
        }
      }
  } else {
    // Q/K path, layout (b,h,s,d), fused RoPE.
    // Pair (2p,2p+1) lives in lanes (lr, lr^1): x1 = even-lane val,
    // x2 = odd-lane val; even out = x1*cs - x2*sn; odd out = x1*sn + x2*cs.
    u16* Ch = (u16*)C;
    int pj[4];
#pragma unroll
    for (int j = 0; j < 4; ++j) pj[j] = (ncol[j] & (DH - 1)) >> 1;
    const bool odd = (lr & 1) != 0;
#pragma unroll
    for (int i = 0; i < 4; ++i)
#pragma unroll
      for (int r = 0; r < 4; ++r) {
        const int m = m0 + wm + 16 * i + lg * 4 + r;
        const int b = m >> 11, s = m & (SEQ - 1);
        const float2* trow = (const float2*)rtab + s * 64;
#pragma unroll
        for (int j = 0; j < 4; ++j) {
          const float val = acc[i][j][r] + bj[j];
          const float partner = __shfl_xor(val, 1);
          const float2 cssn = trow[pj[j]];
          const float outv = odd ? fmaf(partner, cssn.y, val * cssn.x)
                                 : fmaf(partner, -cssn.y, val * cssn.x);
          const int h = ncol[j] >> 7, d = ncol[j] & (DH - 1);
          Ch[((size_t)((b * NH + h) * SEQ + s)) * DH + d] = f2bf(outv);
        }
      }
  }
}

// ---------------------------------------------------------------------------
// RoPE in-place on bf16 Q and K, layout (b,h,s,d). (fallback path only)
// ---------------------------------------------------------------------------
__global__ void rope_kernel(u16* __restrict__ Q, u16* __restrict__ K) {
  const int idx = blockIdx.x * blockDim.x + threadIdx.x;
  const int p = idx & 63;
  const int s = (idx >> 6) & (SEQ - 1);
  const int bh = idx >> 17;
  if (bh >= NBH) return;
  const float freq = exp2f(-(float)p * (13.287712379549449f / 64.0f));
  const float ang = (float)s * freq;
  float sn, cs;
  sincosf(ang, &sn, &cs);
  const size_t base = ((size_t)bh * SEQ + s) * DH + 2 * p;
  {
    const u32 qq = *(const u32*)(Q + base);
    const float x1 = bf2f((u16)(qq & 0xffffu)), x2 = bf2f((u16)(qq >> 16));
    *(u32*)(Q + base) =
        (u32)f2bf(x1 * cs - x2 * sn) | ((u32)f2bf(x1 * sn + x2 * cs) << 16);
  }
  {
    const u32 kk = *(const u32*)(K + base);
    const float x1 = bf2f((u16)(kk & 0xffffu)), x2 = bf2f((u16)(kk >> 16));
    *(u32*)(K + base) =
        (u32)f2bf(x1 * cs - x2 * sn) | ((u32)f2bf(x1 * sn + x2 * cs) << 16);
  }
}

// ---------------------------------------------------------------------------
// Flash attention, causal (unchanged from round 2).
// ---------------------------------------------------------------------------
__global__ __launch_bounds__(256, 2) void attn_kernel(
    const u16* __restrict__ Q, const u16* __restrict__ K,
    const u16* __restrict__ Vt, u16* __restrict__ Oflat) {
  __shared__ u16 Ks[2][64 * 128];  // 2 x 16 KB, double-buffered, swizzled
  __shared__ u16 Vts[128 * 64];    // 16 KB, swizzled chunks
  __shared__ u16 Ps[4 * 32 * 72];  // 18 KB, padded (stride 72)
  const int tid = threadIdx.x;
  const int wave = tid >> 6, lane = tid & 63;
  const int lr = lane & 15, lg = lane >> 4;
  // flat remap: XCD locality on bh, complementary qt pairing on rounds
  const int L = blockIdx.y * 16 + blockIdx.x;
  const int bh = L & 31;
  const int t = L >> 5;
  const int qt = (t < 8) ? t : 23 - t;
  const size_t qk0 = (size_t)bh * SEQ * DH;
  const int q0 = qt * 128 + wave * 32;
  const float C = 0.12752602f;  // (1/sqrt(128)) * log2(e)
  const float RTHR = 62.7f;     // defer-rescale threshold = 8 / C

  short8 qf[2][4];
#pragma unroll
  for (int i = 0; i < 2; ++i)
#pragma unroll
    for (int kb = 0; kb < 4; ++kb)
      qf[i][kb] = *(const short8*)(Q + qk0 + (size_t)(q0 + 16 * i + lr) * DH +
                                   kb * 32 + lg * 8);

  floatx4 o[2][9];  // jd==8 is the l-column (P . ones)
#pragma unroll
  for (int i = 0; i < 2; ++i)
#pragma unroll
    for (int jd = 0; jd < 9; ++jd) {
      floatx4 z = {0.f, 0.f, 0.f, 0.f};
      o[i][jd] = z;
    }
  float mrun[2] = {-1e38f, -1e38f};

  const short8 onesv = {16256, 16256, 16256, 16256,
                        16256, 16256, 16256, 16256};  // bf16 1.0 x8

  u16* myP = &Ps[wave * 32 * 72];
  const int nkt = 2 * qt + 2;

  // prologue: stage K(0) into Ks[0]
#pragma unroll
  for (int p = 0; p < 4; ++p) {
    const int s = p * 256 + tid;
    const int row = s >> 4, c = s & 15;
    const int g = c ^ (row & 15);
    async_load16(K + qk0 + (size_t)row * DH + g * 8,
                 &Ks[0][(p * 256 + wave * 64) * 8]);
  }
  __syncthreads();

  for (int kt = 0; kt < nkt; ++kt) {
    const int cur = kt & 1, nb = cur ^ 1;
    const int kn = (kt + 1 < nkt) ? kt + 1 : kt;  // clamp last prefetch
    // issue V(kt) stage: 128 rows x 8 chunks, physical chunk = c ^ (row&7)
#pragma unroll
    for (int p = 0; p < 4; ++p) {
      const int s = p * 256 + tid;
      const int row = s >> 3, c = s & 7;
      const int g = c ^ (row & 7);
      async_load16(Vt + (size_t)bh * DH * SEQ + (size_t)row * SEQ + kt * 64 + g * 8,
                   &Vts[(p * 256 + wave * 64) * 8]);
    }
    // issue K(kt+1) stage into the other buffer
#pragma unroll
    for (int p = 0; p < 4; ++p) {
      const int s = p * 256 + tid;
      const int row = s >> 4, c = s & 15;
      const int g = c ^ (row & 15);
      async_load16(K + qk0 + (size_t)(kn * 64 + row) * DH + g * 8,
                   &Ks[nb][(p * 256 + wave * 64) * 8]);
    }

    // S^T = K Q^T strip (swapped operands): lane holds q = q0+16i+lr,
    // kpos = kt*64 + 16j + 4lg + r
    floatx4 st[4][2];
#pragma unroll
    for (int j = 0; j < 4; ++j)
#pragma unroll
      for (int i = 0; i < 2; ++i) {
        floatx4 z = {0.f, 0.f, 0.f, 0.f};
        st[j][i] = z;
      }
#pragma unroll
    for (int kb = 0; kb < 4; ++kb) {
      short8 kf[4];
#pragma unroll
      for (int j = 0; j < 4; ++j)
        kf[j] = *(const short8*)&Ks[cur][(16 * j + lr) * 128 +
                                         (((kb * 4 + lg) ^ lr)) * 8];
      __builtin_amdgcn_s_setprio(1);
#pragma unroll
      for (int j = 0; j < 4; ++j)
#pragma unroll
        for (int i = 0; i < 2; ++i)
          st[j][i] = __builtin_amdgcn_mfma_f32_16x16x32_bf16(kf[j], qf[i][kb],
                                                             st[j][i], 0, 0, 0);
      __builtin_amdgcn_s_setprio(0);
    }

    // causal mask on raw scores (diagonal tiles only)
    if (kt >= 2 * qt) {
#pragma unroll
      for (int j = 0; j < 4; ++j)
#pragma unroll
        for (int i = 0; i < 2; ++i)
#pragma unroll
          for (int r = 0; r < 4; ++r) {
            const int kpos = kt * 64 + 16 * j + 4 * lg + r;
            const int qpos = q0 + 16 * i + lr;
            if (kpos > qpos) st[j][i][r] = -1e30f;
          }
    }

    // row max: 15 in-register fmax + 2 cross-group shfl_xor per i
    float mx[2];
#pragma unroll
    for (int i = 0; i < 2; ++i) {
      float m0v = fmaxf(fmaxf(st[0][i][0], st[0][i][1]),
                        fmaxf(st[0][i][2], st[0][i][3]));
      float m1v = fmaxf(fmaxf(st[1][i][0], st[1][i][1]),
                        fmaxf(st[1][i][2], st[1][i][3]));
      float m2v = fmaxf(fmaxf(st[2][i][0], st[2][i][1]),
                        fmaxf(st[2][i][2], st[2][i][3]));
      float m3v = fmaxf(fmaxf(st[3][i][0], st[3][i][1]),
                        fmaxf(st[3][i][2], st[3][i][3]));
      float m = fmaxf(fmaxf(m0v, m1v), fmaxf(m2v, m3v));
      m = fmaxf(m, __shfl_xor(m, 16));
      m = fmaxf(m, __shfl_xor(m, 32));
      mx[i] = m;
    }
    const float grow = fmaxf(mx[0] - mrun[0], mx[1] - mrun[1]);
    if (!__all(grow <= RTHR)) {
      float aS[2];
#pragma unroll
      for (int i = 0; i < 2; ++i) {
        const float mn = fmaxf(mrun[i], mx[i]);
        aS[i] = exp2f((mrun[i] - mn) * C);
        mrun[i] = mn;
      }
      // redistribute alpha from S-layout (q=16i+lr) to O-layout (q=16i+4lg+r)
#pragma unroll
      for (int i = 0; i < 2; ++i)
#pragma unroll
        for (int r = 0; r < 4; ++r) {
          const float aO = __shfl(aS[i], 4 * lg + r);
#pragma unroll
          for (int jd = 0; jd < 9; ++jd) o[i][jd][r] *= aO;
        }
    }
    float negMC[2];
#pragma unroll
    for (int i = 0; i < 2; ++i) negMC[i] = -mrun[i] * C;

    // P = exp2(s*C - m*C); pack 4 bf16 per (i,j) and write one b64
#pragma unroll
    for (int i = 0; i < 2; ++i)
#pragma unroll
      for (int j = 0; j < 4; ++j) {
        const float p0 = exp2f(fmaf(st[j][i][0], C, negMC[i]));
        const float p1 = exp2f(fmaf(st[j][i][1], C, negMC[i]));
        const float p2 = exp2f(fmaf(st[j][i][2], C, negMC[i]));
        const float p3 = exp2f(fmaf(st[j][i][3], C, negMC[i]));
        uint2v w;
        w[0] = (u32)f2bf(p0) | ((u32)f2bf(p1) << 16);
        w[1] = (u32)f2bf(p2) | ((u32)f2bf(p3) << 16);
        *(uint2v*)&myP[(16 * i + lr) * 72 + 16 * j + 4 * lg] = w;
      }

    // drain our ds_writes of P before reading them back as A-fragments
    asm volatile("s_waitcnt lgkmcnt(0)" ::: "memory");
    __syncthreads();  // drains vmcnt: V(kt) and K(kt+1) have landed

#pragma unroll
    for (int kb = 0; kb < 2; ++kb) {
      short8 pf[2];
#pragma unroll
      for (int i = 0; i < 2; ++i)
        pf[i] = *(const short8*)&myP[(16 * i + lr) * 72 + kb * 32 + lg * 8];
      __builtin_amdgcn_s_setprio(1);
#pragma unroll
      for (int jd = 0; jd < 8; ++jd) {
        const short8 vf = *(const short8*)&Vts[(16 * jd + lr) * 64 +
                                               (((kb * 4 + lg) ^ (lr & 7))) * 8];
#pragma unroll
        for (int i = 0; i < 2; ++i)
          o[i][jd] = __builtin_amdgcn_mfma_f32_16x16x32_bf16(pf[i], vf, o[i][jd],
                                                             0, 0, 0);
      }
      // l-column: row sums of P via MFMA with an all-ones B fragment
#pragma unroll
      for (int i = 0; i < 2; ++i)
        o[i][8] = __builtin_amdgcn_mfma_f32_16x16x32_bf16(pf[i], onesv, o[i][8],
                                                          0, 0, 0);
      __builtin_amdgcn_s_setprio(0);
    }
    __syncthreads();  // all waves done with Vts / Ks[cur] before next overwrite
  }

  const int b = bh >> 4, h = bh & (NH - 1);
#pragma unroll
  for (int i = 0; i < 2; ++i)
#pragma unroll
    for (int r = 0; r < 4; ++r) {
      const int qpos = q0 + 16 * i + lg * 4 + r;
      const float inv = 1.0f / o[i][8][r];
      u16* dst = Oflat + ((size_t)(b * SEQ + qpos)) * D_MODEL + h * DH;
#pragma unroll
      for (int jd = 0; jd < 8; ++jd) dst[16 * jd + lr] = f2bf(o[i][jd][r] * inv);
    }
}

// ---------------------------------------------------------------------------
// Round-1 fallback GEMM (f32 sources) — used only if ws too small.
// ---------------------------------------------------------------------------
template <int ABF16>
__global__ __launch_bounds__(256, 2) void gemm_kernel(
    const void* __restrict__ Aptr, const float* __restrict__ W,
    const float* __restrict__ bias, void* __restrict__ Cptr, const int mode) {
  __shared__ u16 As[128 * 72];
  __shared__ u16 Bs[128 * 72];
  const int tid = threadIdx.x;
  const int wave = tid >> 6, lane = tid & 63;
  const int lr = lane & 15, lg = lane >> 4;
  const int m0 = blockIdx.y * 128, n0 = blockIdx.x * 128;
  const int wm = (wave & 1) * 64, wn = (wave >> 1) * 64;

  floatx4 acc[4][4];
#pragma unroll
  for (int i = 0; i < 4; ++i)
#pragma unroll
    for (int j = 0; j < 4; ++j) {
      floatx4 z = {0.f, 0.f, 0.f, 0.f};
      acc[i][j] = z;
    }

  for (int kt = 0; kt < D_MODEL; kt += 64) {
    if (ABF16) {
      const u16* A = (const u16*)Aptr;
      const int row0 = tid >> 3, c8 = (tid & 7) * 8;
#pragma unroll
      for (int p = 0; p < 4; ++p) {
        const int row = row0 + p * 32;
        *(short8*)&As[row * 72 + c8] =
            *(const short8*)(A + (size_t)(m0 + row) * D_MODEL + kt + c8);
      }
    } else {
      const float* A = (const float*)Aptr;
      const int row0 = tid >> 4, c4 = (tid & 15) * 4;
#pragma unroll
      for (int p = 0; p < 8; ++p) {
        const int row = row0 + p * 16;
        const floatx4 v =
            *(const floatx4*)(A + (size_t)(m0 + row) * D_MODEL + kt + c4);
        ushort4v h;
        h[0] = f2bf(v[0]); h[1] = f2bf(v[1]); h[2] = f2bf(v[2]); h[3] = f2bf(v[3]);
        *(ushort4v*)&As[row * 72 + c4] = h;
      }
    }
    {
      const int row0 = tid >> 4, c4 = (tid & 15) * 4;
#pragma unroll
      for (int p = 0; p < 8; ++p) {
        const int row = row0 + p * 16;
        const floatx4 v =
            *(const floatx4*)(W + (size_t)(n0 + row) * D_MODEL + kt + c4);
        ushort4v h;
        h[0] = f2bf(v[0]); h[1] = f2bf(v[1]); h[2] = f2bf(v[2]); h[3] = f2bf(v[3]);
        *(ushort4v*)&Bs[row * 72 + c4] = h;
      }
    }
    __syncthreads();
#pragma unroll
    for (int ks = 0; ks < 2; ++ks) {
      short8 af[4], bfr[4];
#pragma unroll
      for (int i = 0; i < 4; ++i)
        af[i] = *(const short8*)&As[(wm + 16 * i + lr) * 72 + ks * 32 + lg * 8];
#pragma unroll
      for (int j = 0; j < 4; ++j)
        bfr[j] = *(const short8*)&Bs[(wn + 16 * j + lr) * 72 + ks * 32 + lg * 8];
#pragma unroll
      for (int i = 0; i < 4; ++i)
#pragma unroll
        for (int j = 0; j < 4; ++j)
          acc[i][j] = __builtin_amdgcn_mfma_f32_16x16x32_bf16(af[i], bfr[j],
                                                              acc[i][j], 0, 0, 0);
    }
    __syncthreads();
  }

  float bj[4];
  int ncol[4];
#pragma unroll
  for (int j = 0; j < 4; ++j) {
    ncol[j] = n0 + wn + 16 * j + lr;
    bj[j] = bias[ncol[j]];
  }

  if (mode == 3) {
    float* C = (float*)Cptr;
#pragma unroll
    for (int i = 0; i < 4; ++i)
#pragma unroll
      for (int r = 0; r < 4; ++r) {
        const int m = m0 + wm + 16 * i + lg * 4 + r;
#pragma unroll
        for (int j = 0; j < 4; ++j)
          C[(size_t)m * D_MODEL + ncol[j]] = acc[i][j][r] + bj[j];
      }
  } else if (mode == 2) {
    u16* C = (u16*)Cptr;
#pragma unroll
    for (int i = 0; i < 4; ++i)
#pragma unroll
      for (int r = 0; r < 4; ++r) {
        const int m = m0 + wm + 16 * i + lg * 4 + r;
        const int b = m >> 11, s = m & (SEQ - 1);
#pragma unroll
        for (int j = 0; j < 4; ++j) {
          const int h = ncol[j] >> 7, d = ncol[j] & (DH - 1);
          C[((size_t)((b * NH + h) * DH + d)) * SEQ + s] = f2bf(acc[i][j][r] + bj[j]);
        }
      }
  } else {
    u16* C = (u16*)Cptr;
#pragma unroll
    for (int i = 0; i < 4; ++i)
#pragma unroll
      for (int r = 0; r < 4; ++r) {
        const int m = m0 + wm + 16 * i + lg * 4 + r;
        const int b = m >> 11, s = m & (SEQ - 1);
#pragma unroll
        for (int j = 0; j < 4; ++j) {
          const int h = ncol[j] >> 7, d = ncol[j] & (DH - 1);
          C[((size_t)((b * NH + h) * SEQ + s)) * DH + d] = f2bf(acc[i][j][r] + bj[j]);
        }
      }
  }
}

// ---------------------------------------------------------------------------
extern "C" void kernel_launch(void* const* d_in, const int* in_sizes, int n_in,
                              void* d_out, int out_size, void* d_ws,
                              size_t ws_size, hipStream_t stream) {
  const float* x = (const float*)d_in[0];
  const float* Wq = (const float*)d_in[1];
  const float* bq = (const float*)d_in[2];
  const float* Wk = (const float*)d_in[3];
  const float* bk = (const float*)d_in[4];
  const float* Wv = (const float*)d_in[5];
  const float* bv = (const float*)d_in[6];
  const float* Wo = (const float*)d_in[7];
  const float* bo = (const float*)d_in[8];
  float* out = (float*)d_out;

  const size_t E = (size_t)NBH * SEQ * DH;
  const size_t WE = (size_t)D_MODEL * D_MODEL;
  const size_t need = (4 * E + 3 * WE) * sizeof(u16);  // 92.3 MB

  const dim3 gb(256);

  if (ws_size >= need) {
    u16* xb = (u16*)d_ws;
    u16* wqb = xb + E;
    u16* wkb = wqb + WE;
    u16* wvb = wkb + WE;
    u16* q = wvb + WE;
    u16* k = q + E;
    u16* vt = k + E;
    u16* aflat = xb;   // xb dead after QKV GEMM
    u16* wob = q;      // q dead after attention
    // RoPE table scratch lives in d_out (dead until the final GEMM, which
    // overwrites all of it). 1 MB = SEQ*64*2 floats.
    float* rtab = out;

    cvt4_kernel<<<dim3(10368), gb, 0, stream>>>(x, Wq, Wk, Wv, xb, wqb, wkb,
                                                wvb, rtab);

    gemm_async<<<dim3(48, 32), gb, 0, stream>>>(xb, wqb, wkb, wvb, bq, bk, bv,
                                                q, k, vt, rtab, 1);
    attn_kernel<<<dim3(SEQ / 128, NBH), gb, 0, stream>>>(q, k, vt, aflat);
    cvt_kernel<<<dim3((int)(WE / 2048)), gb, 0, stream>>>(Wo, wob, (int)WE);
    gemm_async<<<dim3(16, 32), gb, 0, stream>>>(aflat, wob, nullptr, nullptr,
                                                bo, nullptr, nullptr, out,
                                                nullptr, nullptr, nullptr, 0);
  } else {
    u16* q = (u16*)d_ws;
    u16* k = q + E;
    u16* vt = k + E;
    u16* aflat = vt + E;
    const dim3 gg(D_MODEL / 128, (2 * SEQ) / 128);
    gemm_kernel<0><<<gg, gb, 0, stream>>>(x, Wq, bq, q, 0);
    gemm_kernel<0><<<gg, gb, 0, stream>>>(x, Wk, bk, k, 1);
    gemm_kernel<0><<<gg, gb, 0, stream>>>(x, Wv, bv, vt, 2);
    rope_kernel<<<dim3((NBH * SEQ * (DH / 2)) / 256), dim3(256), 0, stream>>>(q, k);
    attn_kernel<<<dim3(SEQ / 128, NBH), gb, 0, stream>>>(q, k, vt, aflat);
    gemm_kernel<1><<<gg, gb, 0, stream>>>(aflat, Wo, bo, out, 3);
  }
}

// Round 4
// 398.589 us; speedup vs baseline: 1.0129x; 1.0129x over previous
//
#include <hip/hip_runtime.h>
#include <math.h>

#define D_MODEL 2048
#define NH 16
#define DH 128
#define SEQ 2048
#define NBH 32  // batch * heads

typedef unsigned short u16;
typedef unsigned int u32;
typedef __attribute__((ext_vector_type(8))) short short8;
typedef __attribute__((ext_vector_type(4))) float floatx4;
typedef __attribute__((ext_vector_type(2))) unsigned int uint2v;
typedef __attribute__((ext_vector_type(4))) unsigned short ushort4v;

__device__ __forceinline__ u16 f2bf(float f) {
  u32 u = __builtin_bit_cast(u32, f);
  return (u16)((u + 0x8000u) >> 16);
}
__device__ __forceinline__ float bf2f(u16 h) {
  return __builtin_bit_cast(float, (u32)h << 16);
}

// async global->LDS, 16B per lane. LDS dest = wave-uniform base + lane*16.
__device__ __forceinline__ void async_load16(const u16* g, u16* l) {
  __builtin_amdgcn_global_load_lds(
      (const __attribute__((address_space(1))) void*)g,
      (__attribute__((address_space(3))) void*)l, 16, 0, 0);
}

// ---------------------------------------------------------------------------
// f32 -> bf16 elementwise convert. n multiple of 2048. 8 elems/thread.
// ---------------------------------------------------------------------------
__global__ void cvt_kernel(const float* __restrict__ src, u16* __restrict__ dst,
                           int n) {
  const int i = (blockIdx.x * 256 + threadIdx.x) * 8;
  if (i >= n) return;
  const floatx4 a = *(const floatx4*)(src + i);
  const floatx4 b = *(const floatx4*)(src + i + 4);
  short8 h;
  h[0] = (short)f2bf(a[0]); h[1] = (short)f2bf(a[1]);
  h[2] = (short)f2bf(a[2]); h[3] = (short)f2bf(a[3]);
  h[4] = (short)f2bf(b[0]); h[5] = (short)f2bf(b[1]);
  h[6] = (short)f2bf(b[2]); h[7] = (short)f2bf(b[3]);
  *(short8*)(dst + i) = h;
}

// Merged upfront conversions: x (4096 blocks), Wq/Wk/Wv (2048 each), plus
// 128 blocks generating the RoPE cos/sin table (SEQ x 64 float2 = 1 MB).
__global__ void cvt4_kernel(const float* __restrict__ x,
                            const float* __restrict__ wq,
                            const float* __restrict__ wk,
                            const float* __restrict__ wv, u16* __restrict__ xb,
                            u16* __restrict__ wqb, u16* __restrict__ wkb,
                            u16* __restrict__ wvb, float* __restrict__ rtab) {
  const int blk = blockIdx.x;
  if (blk >= 10240) {
    // RoPE table: entry e = (s, p): rtab[2e] = cos(s*freq_p), rtab[2e+1]=sin
    const int e0 = ((blk - 10240) * 256 + threadIdx.x) * 4;
#pragma unroll
    for (int e = e0; e < e0 + 4; ++e) {
      const int s = e >> 6, p = e & 63;
      const float freq = exp2f(-(float)p * (13.287712379549449f / 64.0f));
      float sn, cs;
      sincosf((float)s * freq, &sn, &cs);
      rtab[2 * e] = cs;
      rtab[2 * e + 1] = sn;
    }
    return;
  }
  const float* src;
  u16* dst;
  int base;
  if (blk < 4096) {
    src = x; dst = xb; base = blk;
  } else if (blk < 6144) {
    src = wq; dst = wqb; base = blk - 4096;
  } else if (blk < 8192) {
    src = wk; dst = wkb; base = blk - 6144;
  } else {
    src = wv; dst = wvb; base = blk - 8192;
  }
  const int i = (base * 256 + threadIdx.x) * 8;
  const floatx4 a = *(const floatx4*)(src + i);
  const floatx4 b = *(const floatx4*)(src + i + 4);
  short8 h;
  h[0] = (short)f2bf(a[0]); h[1] = (short)f2bf(a[1]);
  h[2] = (short)f2bf(a[2]); h[3] = (short)f2bf(a[3]);
  h[4] = (short)f2bf(b[0]); h[5] = (short)f2bf(b[1]);
  h[6] = (short)f2bf(b[2]); h[7] = (short)f2bf(b[3]);
  *(short8*)(dst + i) = h;
}

// ---------------------------------------------------------------------------
// bf16 GEMM — round-2 single-buffered structure (measured 100 µs QKV,
// MfmaUtil 46.6%; the round-3 double-buffer REGRESSED to 154 µs by halving
// resident blocks: inter-block overlap > intra-block prefetch here).
// Kept from round 3: fused RoPE epilogue for Q/K (modes 0/1) via cos/sin
// table + shfl_xor(1) lane pairing.
// ---------------------------------------------------------------------------
__global__ __launch_bounds__(256, 2) void gemm_async(
    const u16* __restrict__ A, const u16* __restrict__ W0,
    const u16* __restrict__ W1, const u16* __restrict__ W2,
    const float* __restrict__ b0, const float* __restrict__ b1,
    const float* __restrict__ b2, void* __restrict__ C0, void* __restrict__ C1,
    void* __restrict__ C2, const float* __restrict__ rtab, const int qkv) {
  __shared__ u16 As[128 * 64];
  __shared__ u16 Bs[128 * 64];
  const int tid = threadIdx.x;
  const int wave = tid >> 6, lane = tid & 63;
  const int lr = lane & 15, lg = lane >> 4;
  const int m0 = blockIdx.y * 128;
  const int wm = (wave & 1) * 64, wn = (wave >> 1) * 64;

  int n0, mode;
  const u16* W;
  const float* bias;
  void* C;
  if (qkv) {
    const int which = blockIdx.x >> 4;
    n0 = (blockIdx.x & 15) * 128;
    W = which == 0 ? W0 : which == 1 ? W1 : W2;
    bias = which == 0 ? b0 : which == 1 ? b1 : b2;
    C = which == 0 ? C0 : which == 1 ? C1 : C2;
    mode = which;
  } else {
    n0 = blockIdx.x * 128;
    W = W0; bias = b0; C = C0; mode = 3;
  }

  floatx4 acc[4][4];
#pragma unroll
  for (int i = 0; i < 4; ++i)
#pragma unroll
    for (int j = 0; j < 4; ++j) {
      floatx4 z = {0.f, 0.f, 0.f, 0.f};
      acc[i][j] = z;
    }

  for (int kt = 0; kt < D_MODEL; kt += 64) {
#pragma unroll
    for (int p = 0; p < 4; ++p) {
      const int s = p * 256 + tid;
      const int row = s >> 3, c = s & 7;
      const int g = c ^ (row & 7);
      async_load16(A + (size_t)(m0 + row) * D_MODEL + kt + g * 8,
                   &As[(p * 256 + wave * 64) * 8]);
    }
#pragma unroll
    for (int p = 0; p < 4; ++p) {
      const int s = p * 256 + tid;
      const int row = s >> 3, c = s & 7;
      const int g = c ^ (row & 7);
      async_load16(W + (size_t)(n0 + row) * D_MODEL + kt + g * 8,
                   &Bs[(p * 256 + wave * 64) * 8]);
    }
    __syncthreads();

#pragma unroll
    for (int ks = 0; ks < 2; ++ks) {
      short8 af[4], bfr[4];
      const int ch = (ks * 4 + lg) ^ (lr & 7);
#pragma unroll
      for (int i = 0; i < 4; ++i)
        af[i] = *(const short8*)&As[(wm + 16 * i + lr) * 64 + ch * 8];
#pragma unroll
      for (int j = 0; j < 4; ++j)
        bfr[j] = *(const short8*)&Bs[(wn + 16 * j + lr) * 64 + ch * 8];
#pragma unroll
      for (int i = 0; i < 4; ++i)
#pragma unroll
        for (int j = 0; j < 4; ++j)
          acc[i][j] = __builtin_amdgcn_mfma_f32_16x16x32_bf16(af[i], bfr[j],
                                                              acc[i][j], 0, 0, 0);
    }
    __syncthreads();
  }

  float bj[4];
  int ncol[4];
#pragma unroll
  for (int j = 0; j < 4; ++j) {
    ncol[j] = n0 + wn + 16 * j + lr;
    bj[j] = bias[ncol[j]];
  }

  if (mode == 3) {
    float* Cf = (float*)C;
#pragma unroll
    for (int i = 0; i < 4; ++i)
#pragma unroll
      for (int r = 0; r < 4; ++r) {
        const int m = m0 + wm + 16 * i + lg * 4 + r;
#pragma unroll
        for (int j = 0; j < 4; ++j)
          Cf[(size_t)m * D_MODEL + ncol[j]] = acc[i][j][r] + bj[j];
      }
  } else if (mode == 2) {
    u16* Ch = (u16*)C;
#pragma unroll
    for (int i = 0; i < 4; ++i)
#pragma unroll
      for (int r = 0; r < 4; ++r) {
        const int m = m0 + wm + 16 * i + lg * 4 + r;
        const int b = m >> 11, s = m & (SEQ - 1);
#pragma unroll
        for (int j = 0; j < 4; ++j) {
          const int h = ncol[j] >> 7, d = ncol[j] & (DH - 1);
          Ch[((size_t)((b * NH + h) * DH + d)) * SEQ + s] =
              f2bf(acc[i][j][r] + bj[j]);
        }
      }
  } else {
    // Q/K path, layout (b,h,s,d), fused RoPE.
    // Pair (2p,2p+1) lives in lanes (lr, lr^1): x1 = even-lane val,
    // x2 = odd-lane val; even out = x1*cs - x2*sn; odd out = x1*sn + x2*cs.
    u16* Ch = (u16*)C;
    int pj[4];
#pragma unroll
    for (int j = 0; j < 4; ++j) pj[j] = (ncol[j] & (DH - 1)) >> 1;
    const bool odd = (lr & 1) != 0;
#pragma unroll
    for (int i = 0; i < 4; ++i)
#pragma unroll
      for (int r = 0; r < 4; ++r) {
        const int m = m0 + wm + 16 * i + lg * 4 + r;
        const int b = m >> 11, s = m & (SEQ - 1);
        const float2* trow = (const float2*)rtab + s * 64;
#pragma unroll
        for (int j = 0; j < 4; ++j) {
          const float val = acc[i][j][r] + bj[j];
          const float partner = __shfl_xor(val, 1);
          const float2 cssn = trow[pj[j]];
          const float outv = odd ? fmaf(partner, cssn.y, val * cssn.x)
                                 : fmaf(partner, -cssn.y, val * cssn.x);
          const int h = ncol[j] >> 7, d = ncol[j] & (DH - 1);
          Ch[((size_t)((b * NH + h) * SEQ + s)) * DH + d] = f2bf(outv);
        }
      }
  }
}

// ---------------------------------------------------------------------------
// RoPE in-place on bf16 Q and K, layout (b,h,s,d). (fallback path only)
// ---------------------------------------------------------------------------
__global__ void rope_kernel(u16* __restrict__ Q, u16* __restrict__ K) {
  const int idx = blockIdx.x * blockDim.x + threadIdx.x;
  const int p = idx & 63;
  const int s = (idx >> 6) & (SEQ - 1);
  const int bh = idx >> 17;
  if (bh >= NBH) return;
  const float freq = exp2f(-(float)p * (13.287712379549449f / 64.0f));
  const float ang = (float)s * freq;
  float sn, cs;
  sincosf(ang, &sn, &cs);
  const size_t base = ((size_t)bh * SEQ + s) * DH + 2 * p;
  {
    const u32 qq = *(const u32*)(Q + base);
    const float x1 = bf2f((u16)(qq & 0xffffu)), x2 = bf2f((u16)(qq >> 16));
    *(u32*)(Q + base) =
        (u32)f2bf(x1 * cs - x2 * sn) | ((u32)f2bf(x1 * sn + x2 * cs) << 16);
  }
  {
    const u32 kk = *(const u32*)(K + base);
    const float x1 = bf2f((u16)(kk & 0xffffu)), x2 = bf2f((u16)(kk >> 16));
    *(u32*)(K + base) =
        (u32)f2bf(x1 * cs - x2 * sn) | ((u32)f2bf(x1 * sn + x2 * cs) << 16);
  }
}

// ---------------------------------------------------------------------------
// Flash attention, causal (unchanged from round 2).
// ---------------------------------------------------------------------------
__global__ __launch_bounds__(256, 2) void attn_kernel(
    const u16* __restrict__ Q, const u16* __restrict__ K,
    const u16* __restrict__ Vt, u16* __restrict__ Oflat) {
  __shared__ u16 Ks[2][64 * 128];  // 2 x 16 KB, double-buffered, swizzled
  __shared__ u16 Vts[128 * 64];    // 16 KB, swizzled chunks
  __shared__ u16 Ps[4 * 32 * 72];  // 18 KB, padded (stride 72)
  const int tid = threadIdx.x;
  const int wave = tid >> 6, lane = tid & 63;
  const int lr = lane & 15, lg = lane >> 4;
  // flat remap: XCD locality on bh, complementary qt pairing on rounds
  const int L = blockIdx.y * 16 + blockIdx.x;
  const int bh = L & 31;
  const int t = L >> 5;
  const int qt = (t < 8) ? t : 23 - t;
  const size_t qk0 = (size_t)bh * SEQ * DH;
  const int q0 = qt * 128 + wave * 32;
  const float C = 0.12752602f;  // (1/sqrt(128)) * log2(e)
  const float RTHR = 62.7f;     // defer-rescale threshold = 8 / C

  short8 qf[2][4];
#pragma unroll
  for (int i = 0; i < 2; ++i)
#pragma unroll
    for (int kb = 0; kb < 4; ++kb)
      qf[i][kb] = *(const short8*)(Q + qk0 + (size_t)(q0 + 16 * i + lr) * DH +
                                   kb * 32 + lg * 8);

  floatx4 o[2][9];  // jd==8 is the l-column (P . ones)
#pragma unroll
  for (int i = 0; i < 2; ++i)
#pragma unroll
    for (int jd = 0; jd < 9; ++jd) {
      floatx4 z = {0.f, 0.f, 0.f, 0.f};
      o[i][jd] = z;
    }
  float mrun[2] = {-1e38f, -1e38f};

  const short8 onesv = {16256, 16256, 16256, 16256,
                        16256, 16256, 16256, 16256};  // bf16 1.0 x8

  u16* myP = &Ps[wave * 32 * 72];
  const int nkt = 2 * qt + 2;

  // prologue: stage K(0) into Ks[0]
#pragma unroll
  for (int p = 0; p < 4; ++p) {
    const int s = p * 256 + tid;
    const int row = s >> 4, c = s & 15;
    const int g = c ^ (row & 15);
    async_load16(K + qk0 + (size_t)row * DH + g * 8,
                 &Ks[0][(p * 256 + wave * 64) * 8]);
  }
  __syncthreads();

  for (int kt = 0; kt < nkt; ++kt) {
    const int cur = kt & 1, nb = cur ^ 1;
    const int kn = (kt + 1 < nkt) ? kt + 1 : kt;  // clamp last prefetch
    // issue V(kt) stage: 128 rows x 8 chunks, physical chunk = c ^ (row&7)
#pragma unroll
    for (int p = 0; p < 4; ++p) {
      const int s = p * 256 + tid;
      const int row = s >> 3, c = s & 7;
      const int g = c ^ (row & 7);
      async_load16(Vt + (size_t)bh * DH * SEQ + (size_t)row * SEQ + kt * 64 + g * 8,
                   &Vts[(p * 256 + wave * 64) * 8]);
    }
    // issue K(kt+1) stage into the other buffer
#pragma unroll
    for (int p = 0; p < 4; ++p) {
      const int s = p * 256 + tid;
      const int row = s >> 4, c = s & 15;
      const int g = c ^ (row & 15);
      async_load16(K + qk0 + (size_t)(kn * 64 + row) * DH + g * 8,
                   &Ks[nb][(p * 256 + wave * 64) * 8]);
    }

    // S^T = K Q^T strip (swapped operands): lane holds q = q0+16i+lr,
    // kpos = kt*64 + 16j + 4lg + r
    floatx4 st[4][2];
#pragma unroll
    for (int j = 0; j < 4; ++j)
#pragma unroll
      for (int i = 0; i < 2; ++i) {
        floatx4 z = {0.f, 0.f, 0.f, 0.f};
        st[j][i] = z;
      }
#pragma unroll
    for (int kb = 0; kb < 4; ++kb) {
      short8 kf[4];
#pragma unroll
      for (int j = 0; j < 4; ++j)
        kf[j] = *(const short8*)&Ks[cur][(16 * j + lr) * 128 +
                                         (((kb * 4 + lg) ^ lr)) * 8];
      __builtin_amdgcn_s_setprio(1);
#pragma unroll
      for (int j = 0; j < 4; ++j)
#pragma unroll
        for (int i = 0; i < 2; ++i)
          st[j][i] = __builtin_amdgcn_mfma_f32_16x16x32_bf16(kf[j], qf[i][kb],
                                                             st[j][i], 0, 0, 0);
      __builtin_amdgcn_s_setprio(0);
    }

    // causal mask on raw scores (diagonal tiles only)
    if (kt >= 2 * qt) {
#pragma unroll
      for (int j = 0; j < 4; ++j)
#pragma unroll
        for (int i = 0; i < 2; ++i)
#pragma unroll
          for (int r = 0; r < 4; ++r) {
            const int kpos = kt * 64 + 16 * j + 4 * lg + r;
            const int qpos = q0 + 16 * i + lr;
            if (kpos > qpos) st[j][i][r] = -1e30f;
          }
    }

    // row max: 15 in-register fmax + 2 cross-group shfl_xor per i
    float mx[2];
#pragma unroll
    for (int i = 0; i < 2; ++i) {
      float m0v = fmaxf(fmaxf(st[0][i][0], st[0][i][1]),
                        fmaxf(st[0][i][2], st[0][i][3]));
      float m1v = fmaxf(fmaxf(st[1][i][0], st[1][i][1]),
                        fmaxf(st[1][i][2], st[1][i][3]));
      float m2v = fmaxf(fmaxf(st[2][i][0], st[2][i][1]),
                        fmaxf(st[2][i][2], st[2][i][3]));
      float m3v = fmaxf(fmaxf(st[3][i][0], st[3][i][1]),
                        fmaxf(st[3][i][2], st[3][i][3]));
      float m = fmaxf(fmaxf(m0v, m1v), fmaxf(m2v, m3v));
      m = fmaxf(m, __shfl_xor(m, 16));
      m = fmaxf(m, __shfl_xor(m, 32));
      mx[i] = m;
    }
    const float grow = fmaxf(mx[0] - mrun[0], mx[1] - mrun[1]);
    if (!__all(grow <= RTHR)) {
      float aS[2];
#pragma unroll
      for (int i = 0; i < 2; ++i) {
        const float mn = fmaxf(mrun[i], mx[i]);
        aS[i] = exp2f((mrun[i] - mn) * C);
        mrun[i] = mn;
      }
      // redistribute alpha from S-layout (q=16i+lr) to O-layout (q=16i+4lg+r)
#pragma unroll
      for (int i = 0; i < 2; ++i)
#pragma unroll
        for (int r = 0; r < 4; ++r) {
          const float aO = __shfl(aS[i], 4 * lg + r);
#pragma unroll
          for (int jd = 0; jd < 9; ++jd) o[i][jd][r] *= aO;
        }
    }
    float negMC[2];
#pragma unroll
    for (int i = 0; i < 2; ++i) negMC[i] = -mrun[i] * C;

    // P = exp2(s*C - m*C); pack 4 bf16 per (i,j) and write one b64
#pragma unroll
    for (int i = 0; i < 2; ++i)
#pragma unroll
      for (int j = 0; j < 4; ++j) {
        const float p0 = exp2f(fmaf(st[j][i][0], C, negMC[i]));
        const float p1 = exp2f(fmaf(st[j][i][1], C, negMC[i]));
        const float p2 = exp2f(fmaf(st[j][i][2], C, negMC[i]));
        const float p3 = exp2f(fmaf(st[j][i][3], C, negMC[i]));
        uint2v w;
        w[0] = (u32)f2bf(p0) | ((u32)f2bf(p1) << 16);
        w[1] = (u32)f2bf(p2) | ((u32)f2bf(p3) << 16);
        *(uint2v*)&myP[(16 * i + lr) * 72 + 16 * j + 4 * lg] = w;
      }

    // drain our ds_writes of P before reading them back as A-fragments
    asm volatile("s_waitcnt lgkmcnt(0)" ::: "memory");
    __syncthreads();  // drains vmcnt: V(kt) and K(kt+1) have landed

#pragma unroll
    for (int kb = 0; kb < 2; ++kb) {
      short8 pf[2];
#pragma unroll
      for (int i = 0; i < 2; ++i)
        pf[i] = *(const short8*)&myP[(16 * i + lr) * 72 + kb * 32 + lg * 8];
      __builtin_amdgcn_s_setprio(1);
#pragma unroll
      for (int jd = 0; jd < 8; ++jd) {
        const short8 vf = *(const short8*)&Vts[(16 * jd + lr) * 64 +
                                               (((kb * 4 + lg) ^ (lr & 7))) * 8];
#pragma unroll
        for (int i = 0; i < 2; ++i)
          o[i][jd] = __builtin_amdgcn_mfma_f32_16x16x32_bf16(pf[i], vf, o[i][jd],
                                                             0, 0, 0);
      }
      // l-column: row sums of P via MFMA with an all-ones B fragment
#pragma unroll
      for (int i = 0; i < 2; ++i)
        o[i][8] = __builtin_amdgcn_mfma_f32_16x16x32_bf16(pf[i], onesv, o[i][8],
                                                          0, 0, 0);
      __builtin_amdgcn_s_setprio(0);
    }
    __syncthreads();  // all waves done with Vts / Ks[cur] before next overwrite
  }

  const int b = bh >> 4, h = bh & (NH - 1);
#pragma unroll
  for (int i = 0; i < 2; ++i)
#pragma unroll
    for (int r = 0; r < 4; ++r) {
      const int qpos = q0 + 16 * i + lg * 4 + r;
      const float inv = 1.0f / o[i][8][r];
      u16* dst = Oflat + ((size_t)(b * SEQ + qpos)) * D_MODEL + h * DH;
#pragma unroll
      for (int jd = 0; jd < 8; ++jd) dst[16 * jd + lr] = f2bf(o[i][jd][r] * inv);
    }
}

// ---------------------------------------------------------------------------
// Round-1 fallback GEMM (f32 sources) — used only if ws too small.
// ---------------------------------------------------------------------------
template <int ABF16>
__global__ __launch_bounds__(256, 2) void gemm_kernel(
    const void* __restrict__ Aptr, const float* __restrict__ W,
    const float* __restrict__ bias, void* __restrict__ Cptr, const int mode) {
  __shared__ u16 As[128 * 72];
  __shared__ u16 Bs[128 * 72];
  const int tid = threadIdx.x;
  const int wave = tid >> 6, lane = tid & 63;
  const int lr = lane & 15, lg = lane >> 4;
  const int m0 = blockIdx.y * 128, n0 = blockIdx.x * 128;
  const int wm = (wave & 1) * 64, wn = (wave >> 1) * 64;

  floatx4 acc[4][4];
#pragma unroll
  for (int i = 0; i < 4; ++i)
#pragma unroll
    for (int j = 0; j < 4; ++j) {
      floatx4 z = {0.f, 0.f, 0.f, 0.f};
      acc[i][j] = z;
    }

  for (int kt = 0; kt < D_MODEL; kt += 64) {
    if (ABF16) {
      const u16* A = (const u16*)Aptr;
      const int row0 = tid >> 3, c8 = (tid & 7) * 8;
#pragma unroll
      for (int p = 0; p < 4; ++p) {
        const int row = row0 + p * 32;
        *(short8*)&As[row * 72 + c8] =
            *(const short8*)(A + (size_t)(m0 + row) * D_MODEL + kt + c8);
      }
    } else {
      const float* A = (const float*)Aptr;
      const int row0 = tid >> 4, c4 = (tid & 15) * 4;
#pragma unroll
      for (int p = 0; p < 8; ++p) {
        const int row = row0 + p * 16;
        const floatx4 v =
            *(const floatx4*)(A + (size_t)(m0 + row) * D_MODEL + kt + c4);
        ushort4v h;
        h[0] = f2bf(v[0]); h[1] = f2bf(v[1]); h[2] = f2bf(v[2]); h[3] = f2bf(v[3]);
        *(ushort4v*)&As[row * 72 + c4] = h;
      }
    }
    {
      const int row0 = tid >> 4, c4 = (tid & 15) * 4;
#pragma unroll
      for (int p = 0; p < 8; ++p) {
        const int row = row0 + p * 16;
        const floatx4 v =
            *(const floatx4*)(W + (size_t)(n0 + row) * D_MODEL + kt + c4);
        ushort4v h;
        h[0] = f2bf(v[0]); h[1] = f2bf(v[1]); h[2] = f2bf(v[2]); h[3] = f2bf(v[3]);
        *(ushort4v*)&Bs[row * 72 + c4] = h;
      }
    }
    __syncthreads();
#pragma unroll
    for (int ks = 0; ks < 2; ++ks) {
      short8 af[4], bfr[4];
#pragma unroll
      for (int i = 0; i < 4; ++i)
        af[i] = *(const short8*)&As[(wm + 16 * i + lr) * 72 + ks * 32 + lg * 8];
#pragma unroll
      for (int j = 0; j < 4; ++j)
        bfr[j] = *(const short8*)&Bs[(wn + 16 * j + lr) * 72 + ks * 32 + lg * 8];
#pragma unroll
      for (int i = 0; i < 4; ++i)
#pragma unroll
        for (int j = 0; j < 4; ++j)
          acc[i][j] = __builtin_amdgcn_mfma_f32_16x16x32_bf16(af[i], bfr[j],
                                                              acc[i][j], 0, 0, 0);
    }
    __syncthreads();
  }

  float bj[4];
  int ncol[4];
#pragma unroll
  for (int j = 0; j < 4; ++j) {
    ncol[j] = n0 + wn + 16 * j + lr;
    bj[j] = bias[ncol[j]];
  }

  if (mode == 3) {
    float* C = (float*)Cptr;
#pragma unroll
    for (int i = 0; i < 4; ++i)
#pragma unroll
      for (int r = 0; r < 4; ++r) {
        const int m = m0 + wm + 16 * i + lg * 4 + r;
#pragma unroll
        for (int j = 0; j < 4; ++j)
          C[(size_t)m * D_MODEL + ncol[j]] = acc[i][j][r] + bj[j];
      }
  } else if (mode == 2) {
    u16* C = (u16*)Cptr;
#pragma unroll
    for (int i = 0; i < 4; ++i)
#pragma unroll
      for (int r = 0; r < 4; ++r) {
        const int m = m0 + wm + 16 * i + lg * 4 + r;
        const int b = m >> 11, s = m & (SEQ - 1);
#pragma unroll
        for (int j = 0; j < 4; ++j) {
          const int h = ncol[j] >> 7, d = ncol[j] & (DH - 1);
          C[((size_t)((b * NH + h) * DH + d)) * SEQ + s] = f2bf(acc[i][j][r] + bj[j]);
        }
      }
  } else {
    u16* C = (u16*)Cptr;
#pragma unroll
    for (int i = 0; i < 4; ++i)
#pragma unroll
      for (int r = 0; r < 4; ++r) {
        const int m = m0 + wm + 16 * i + lg * 4 + r;
        const int b = m >> 11, s = m & (SEQ - 1);
#pragma unroll
        for (int j = 0; j < 4; ++j) {
          const int h = ncol[j] >> 7, d = ncol[j] & (DH - 1);
          C[((size_t)((b * NH + h) * SEQ + s)) * DH + d] = f2bf(acc[i][j][r] + bj[j]);
        }
      }
  }
}

// ---------------------------------------------------------------------------
extern "C" void kernel_launch(void* const* d_in, const int* in_sizes, int n_in,
                              void* d_out, int out_size, void* d_ws,
                              size_t ws_size, hipStream_t stream) {
  const float* x = (const float*)d_in[0];
  const float* Wq = (const float*)d_in[1];
  const float* bq = (const float*)d_in[2];
  const float* Wk = (const float*)d_in[3];
  const float* bk = (const float*)d_in[4];
  const float* Wv = (const float*)d_in[5];
  const float* bv = (const float*)d_in[6];
  const float* Wo = (const float*)d_in[7];
  const float* bo = (const float*)d_in[8];
  float* out = (float*)d_out;

  const size_t E = (size_t)NBH * SEQ * DH;
  const size_t WE = (size_t)D_MODEL * D_MODEL;
  const size_t need = (4 * E + 3 * WE) * sizeof(u16);  // 92.3 MB

  const dim3 gb(256);

  if (ws_size >= need) {
    u16* xb = (u16*)d_ws;
    u16* wqb = xb + E;
    u16* wkb = wqb + WE;
    u16* wvb = wkb + WE;
    u16* q = wvb + WE;
    u16* k = q + E;
    u16* vt = k + E;
    u16* aflat = xb;   // xb dead after QKV GEMM
    u16* wob = q;      // q dead after attention
    // RoPE table scratch lives in d_out (dead until the final GEMM, which
    // overwrites all of it). 1 MB = SEQ*64*2 floats.
    float* rtab = out;

    cvt4_kernel<<<dim3(10368), gb, 0, stream>>>(x, Wq, Wk, Wv, xb, wqb, wkb,
                                                wvb, rtab);

    gemm_async<<<dim3(48, 32), gb, 0, stream>>>(xb, wqb, wkb, wvb, bq, bk, bv,
                                                q, k, vt, rtab, 1);
    attn_kernel<<<dim3(SEQ / 128, NBH), gb, 0, stream>>>(q, k, vt, aflat);
    cvt_kernel<<<dim3((int)(WE / 2048)), gb, 0, stream>>>(Wo, wob, (int)WE);
    gemm_async<<<dim3(16, 32), gb, 0, stream>>>(aflat, wob, nullptr, nullptr,
                                                bo, nullptr, nullptr, out,
                                                nullptr, nullptr, nullptr, 0);
  } else {
    u16* q = (u16*)d_ws;
    u16* k = q + E;
    u16* vt = k + E;
    u16* aflat = vt + E;
    const dim3 gg(D_MODEL / 128, (2 * SEQ) / 128);
    gemm_kernel<0><<<gg, gb, 0, stream>>>(x, Wq, bq, q, 0);
    gemm_kernel<0><<<gg, gb, 0, stream>>>(x, Wk, bk, k, 1);
    gemm_kernel<0><<<gg, gb, 0, stream>>>(x, Wv, bv, vt, 2);
    rope_kernel<<<dim3((NBH * SEQ * (DH / 2)) / 256), dim3(256), 0, stream>>>(q, k);
    attn_kernel<<<dim3(SEQ / 128, NBH), gb, 0, stream>>>(q, k, vt, aflat);
    gemm_kernel<1><<<gg, gb, 0, stream>>>(aflat, Wo, bo, out, 3);
  }
}

// Round 5
// 377.547 us; speedup vs baseline: 1.0694x; 1.0557x over previous
//
#include <hip/hip_runtime.h>
#include <hip/hip_fp16.h>
#include <math.h>

#define D_MODEL 2048
#define NH 16
#define DH 128
#define SEQ 2048
#define NBH 32  // batch * heads

typedef unsigned short u16;
typedef unsigned int u32;
typedef __attribute__((ext_vector_type(8))) short short8;
typedef __attribute__((ext_vector_type(4))) float floatx4;
typedef __attribute__((ext_vector_type(2))) unsigned int uint2v;
typedef __attribute__((ext_vector_type(4))) unsigned int uint4v;
typedef __attribute__((ext_vector_type(4))) unsigned short ushort4v;

__device__ __forceinline__ u16 f2bf(float f) {
  u32 u = __builtin_bit_cast(u32, f);
  return (u16)((u + 0x8000u) >> 16);
}
__device__ __forceinline__ float bf2f(u16 h) {
  return __builtin_bit_cast(float, (u32)h << 16);
}

// async global->LDS, 16B per lane. LDS dest = wave-uniform base + lane*16.
__device__ __forceinline__ void async_load16(const u16* g, u16* l) {
  __builtin_amdgcn_global_load_lds(
      (const __attribute__((address_space(1))) void*)g,
      (__attribute__((address_space(3))) void*)l, 16, 0, 0);
}

// ---------------------------------------------------------------------------
// f32 -> bf16 elementwise convert. n multiple of 2048. 8 elems/thread.
// ---------------------------------------------------------------------------
__global__ void cvt_kernel(const float* __restrict__ src, u16* __restrict__ dst,
                           int n) {
  const int i = (blockIdx.x * 256 + threadIdx.x) * 8;
  if (i >= n) return;
  const floatx4 a = *(const floatx4*)(src + i);
  const floatx4 b = *(const floatx4*)(src + i + 4);
  short8 h;
  h[0] = (short)f2bf(a[0]); h[1] = (short)f2bf(a[1]);
  h[2] = (short)f2bf(a[2]); h[3] = (short)f2bf(a[3]);
  h[4] = (short)f2bf(b[0]); h[5] = (short)f2bf(b[1]);
  h[6] = (short)f2bf(b[2]); h[7] = (short)f2bf(b[3]);
  *(short8*)(dst + i) = h;
}

// Merged upfront conversions: x (4096 blocks), Wq/Wk/Wv (2048 each), plus
// 128 blocks generating the RoPE table as PACKED half2 (cos|sin<<16):
// SEQ x 64 x u32 = 512 KB. fp16 error 2^-11 << bf16 storage rounding 2^-8.
__global__ void cvt4_kernel(const float* __restrict__ x,
                            const float* __restrict__ wq,
                            const float* __restrict__ wk,
                            const float* __restrict__ wv, u16* __restrict__ xb,
                            u16* __restrict__ wqb, u16* __restrict__ wkb,
                            u16* __restrict__ wvb, u32* __restrict__ rtab) {
  const int blk = blockIdx.x;
  if (blk >= 10240) {
    // RoPE table: entry e = (s, p): low half = cos(s*freq_p), high = sin
    const int e0 = ((blk - 10240) * 256 + threadIdx.x) * 4;
#pragma unroll
    for (int e = e0; e < e0 + 4; ++e) {
      const int s = e >> 6, p = e & 63;
      const float freq = exp2f(-(float)p * (13.287712379549449f / 64.0f));
      float sn, cs;
      sincosf((float)s * freq, &sn, &cs);
      rtab[e] = (u32)__half_as_ushort(__float2half_rn(cs)) |
                ((u32)__half_as_ushort(__float2half_rn(sn)) << 16);
    }
    return;
  }
  const float* src;
  u16* dst;
  int base;
  if (blk < 4096) {
    src = x; dst = xb; base = blk;
  } else if (blk < 6144) {
    src = wq; dst = wqb; base = blk - 4096;
  } else if (blk < 8192) {
    src = wk; dst = wkb; base = blk - 6144;
  } else {
    src = wv; dst = wvb; base = blk - 8192;
  }
  const int i = (base * 256 + threadIdx.x) * 8;
  const floatx4 a = *(const floatx4*)(src + i);
  const floatx4 b = *(const floatx4*)(src + i + 4);
  short8 h;
  h[0] = (short)f2bf(a[0]); h[1] = (short)f2bf(a[1]);
  h[2] = (short)f2bf(a[2]); h[3] = (short)f2bf(a[3]);
  h[4] = (short)f2bf(b[0]); h[5] = (short)f2bf(b[1]);
  h[6] = (short)f2bf(b[2]); h[7] = (short)f2bf(b[3]);
  *(short8*)(dst + i) = h;
}

// ---------------------------------------------------------------------------
// bf16 GEMM — round-2 single-buffered structure (measured 100 µs QKV).
// RoPE fusion v2: the round-4 per-element GLOBAL gather (64 scattered 8B
// loads/thread at the block tail) cost ~25 µs. Now the block's 128x64 table
// slice (32 KB as packed half2) is staged COALESCED into the dead As/Bs LDS
// after the K-loop; epilogue reads LDS (<=4-way conflicts).
// ---------------------------------------------------------------------------
__global__ __launch_bounds__(256, 2) void gemm_async(
    const u16* __restrict__ A, const u16* __restrict__ W0,
    const u16* __restrict__ W1, const u16* __restrict__ W2,
    const float* __restrict__ b0, const float* __restrict__ b1,
    const float* __restrict__ b2, void* __restrict__ C0, void* __restrict__ C1,
    void* __restrict__ C2, const u32* __restrict__ rtab, const int qkv) {
  __shared__ u16 smem[2 * 128 * 64];  // As | Bs, retiled as RoPE table later
  u16* const As = smem;
  u16* const Bs = smem + 128 * 64;
  const int tid = threadIdx.x;
  const int wave = tid >> 6, lane = tid & 63;
  const int lr = lane & 15, lg = lane >> 4;
  const int m0 = blockIdx.y * 128;
  const int wm = (wave & 1) * 64, wn = (wave >> 1) * 64;

  int n0, mode;
  const u16* W;
  const float* bias;
  void* C;
  if (qkv) {
    const int which = blockIdx.x >> 4;
    n0 = (blockIdx.x & 15) * 128;
    W = which == 0 ? W0 : which == 1 ? W1 : W2;
    bias = which == 0 ? b0 : which == 1 ? b1 : b2;
    C = which == 0 ? C0 : which == 1 ? C1 : C2;
    mode = which;
  } else {
    n0 = blockIdx.x * 128;
    W = W0; bias = b0; C = C0; mode = 3;
  }

  floatx4 acc[4][4];
#pragma unroll
  for (int i = 0; i < 4; ++i)
#pragma unroll
    for (int j = 0; j < 4; ++j) {
      floatx4 z = {0.f, 0.f, 0.f, 0.f};
      acc[i][j] = z;
    }

  for (int kt = 0; kt < D_MODEL; kt += 64) {
#pragma unroll
    for (int p = 0; p < 4; ++p) {
      const int s = p * 256 + tid;
      const int row = s >> 3, c = s & 7;
      const int g = c ^ (row & 7);
      async_load16(A + (size_t)(m0 + row) * D_MODEL + kt + g * 8,
                   &As[(p * 256 + wave * 64) * 8]);
    }
#pragma unroll
    for (int p = 0; p < 4; ++p) {
      const int s = p * 256 + tid;
      const int row = s >> 3, c = s & 7;
      const int g = c ^ (row & 7);
      async_load16(W + (size_t)(n0 + row) * D_MODEL + kt + g * 8,
                   &Bs[(p * 256 + wave * 64) * 8]);
    }
    __syncthreads();

#pragma unroll
    for (int ks = 0; ks < 2; ++ks) {
      short8 af[4], bfr[4];
      const int ch = (ks * 4 + lg) ^ (lr & 7);
#pragma unroll
      for (int i = 0; i < 4; ++i)
        af[i] = *(const short8*)&As[(wm + 16 * i + lr) * 64 + ch * 8];
#pragma unroll
      for (int j = 0; j < 4; ++j)
        bfr[j] = *(const short8*)&Bs[(wn + 16 * j + lr) * 64 + ch * 8];
#pragma unroll
      for (int i = 0; i < 4; ++i)
#pragma unroll
        for (int j = 0; j < 4; ++j)
          acc[i][j] = __builtin_amdgcn_mfma_f32_16x16x32_bf16(af[i], bfr[j],
                                                              acc[i][j], 0, 0, 0);
    }
    __syncthreads();
  }

  float bj[4];
  int ncol[4];
#pragma unroll
  for (int j = 0; j < 4; ++j) {
    ncol[j] = n0 + wn + 16 * j + lr;
    bj[j] = bias[ncol[j]];
  }

  if (mode == 3) {
    float* Cf = (float*)C;
#pragma unroll
    for (int i = 0; i < 4; ++i)
#pragma unroll
      for (int r = 0; r < 4; ++r) {
        const int m = m0 + wm + 16 * i + lg * 4 + r;
#pragma unroll
        for (int j = 0; j < 4; ++j)
          Cf[(size_t)m * D_MODEL + ncol[j]] = acc[i][j][r] + bj[j];
      }
  } else if (mode == 2) {
    u16* Ch = (u16*)C;
#pragma unroll
    for (int i = 0; i < 4; ++i)
#pragma unroll
      for (int r = 0; r < 4; ++r) {
        const int m = m0 + wm + 16 * i + lg * 4 + r;
        const int b = m >> 11, s = m & (SEQ - 1);
#pragma unroll
        for (int j = 0; j < 4; ++j) {
          const int h = ncol[j] >> 7, d = ncol[j] & (DH - 1);
          Ch[((size_t)((b * NH + h) * DH + d)) * SEQ + s] =
              f2bf(acc[i][j][r] + bj[j]);
        }
      }
  } else {
    // Q/K path, layout (b,h,s,d), fused RoPE.
    // Stage this block's table slice [s0..s0+128) x 64 (packed half2, 32 KB)
    // coalesced into the now-dead As/Bs LDS, then read it per element.
    u32* tab = (u32*)smem;
    {
      const u32* slice = rtab + (size_t)(m0 & (SEQ - 1)) * 64;
#pragma unroll
      for (int kk = 0; kk < 8; ++kk)
        ((uint4v*)tab)[kk * 256 + tid] = ((const uint4v*)slice)[kk * 256 + tid];
    }
    __syncthreads();
    u16* Ch = (u16*)C;
    int pj[4];
#pragma unroll
    for (int j = 0; j < 4; ++j) pj[j] = (ncol[j] & (DH - 1)) >> 1;
    const bool odd = (lr & 1) != 0;
#pragma unroll
    for (int i = 0; i < 4; ++i)
#pragma unroll
      for (int r = 0; r < 4; ++r) {
        const int mloc = wm + 16 * i + lg * 4 + r;
        const int m = m0 + mloc;
        const int b = m >> 11, s = m & (SEQ - 1);
#pragma unroll
        for (int j = 0; j < 4; ++j) {
          const float val = acc[i][j][r] + bj[j];
          const float partner = __shfl_xor(val, 1);
          const u32 cw = tab[mloc * 64 + pj[j]];
          const float cs = __half2float(__ushort_as_half((u16)(cw & 0xffffu)));
          const float sn = __half2float(__ushort_as_half((u16)(cw >> 16)));
          const float outv = odd ? fmaf(partner, sn, val * cs)
                                 : fmaf(partner, -sn, val * cs);
          const int h = ncol[j] >> 7, d = ncol[j] & (DH - 1);
          Ch[((size_t)((b * NH + h) * SEQ + s)) * DH + d] = f2bf(outv);
        }
      }
  }
}

// ---------------------------------------------------------------------------
// RoPE in-place on bf16 Q and K, layout (b,h,s,d). (fallback path only)
// ---------------------------------------------------------------------------
__global__ void rope_kernel(u16* __restrict__ Q, u16* __restrict__ K) {
  const int idx = blockIdx.x * blockDim.x + threadIdx.x;
  const int p = idx & 63;
  const int s = (idx >> 6) & (SEQ - 1);
  const int bh = idx >> 17;
  if (bh >= NBH) return;
  const float freq = exp2f(-(float)p * (13.287712379549449f / 64.0f));
  const float ang = (float)s * freq;
  float sn, cs;
  sincosf(ang, &sn, &cs);
  const size_t base = ((size_t)bh * SEQ + s) * DH + 2 * p;
  {
    const u32 qq = *(const u32*)(Q + base);
    const float x1 = bf2f((u16)(qq & 0xffffu)), x2 = bf2f((u16)(qq >> 16));
    *(u32*)(Q + base) =
        (u32)f2bf(x1 * cs - x2 * sn) | ((u32)f2bf(x1 * sn + x2 * cs) << 16);
  }
  {
    const u32 kk = *(const u32*)(K + base);
    const float x1 = bf2f((u16)(kk & 0xffffu)), x2 = bf2f((u16)(kk >> 16));
    *(u32*)(K + base) =
        (u32)f2bf(x1 * cs - x2 * sn) | ((u32)f2bf(x1 * sn + x2 * cs) << 16);
  }
}

// ---------------------------------------------------------------------------
// Flash attention, causal (unchanged from round 2).
// ---------------------------------------------------------------------------
__global__ __launch_bounds__(256, 2) void attn_kernel(
    const u16* __restrict__ Q, const u16* __restrict__ K,
    const u16* __restrict__ Vt, u16* __restrict__ Oflat) {
  __shared__ u16 Ks[2][64 * 128];  // 2 x 16 KB, double-buffered, swizzled
  __shared__ u16 Vts[128 * 64];    // 16 KB, swizzled chunks
  __shared__ u16 Ps[4 * 32 * 72];  // 18 KB, padded (stride 72)
  const int tid = threadIdx.x;
  const int wave = tid >> 6, lane = tid & 63;
  const int lr = lane & 15, lg = lane >> 4;
  // flat remap: XCD locality on bh, complementary qt pairing on rounds
  const int L = blockIdx.y * 16 + blockIdx.x;
  const int bh = L & 31;
  const int t = L >> 5;
  const int qt = (t < 8) ? t : 23 - t;
  const size_t qk0 = (size_t)bh * SEQ * DH;
  const int q0 = qt * 128 + wave * 32;
  const float C = 0.12752602f;  // (1/sqrt(128)) * log2(e)
  const float RTHR = 62.7f;     // defer-rescale threshold = 8 / C

  short8 qf[2][4];
#pragma unroll
  for (int i = 0; i < 2; ++i)
#pragma unroll
    for (int kb = 0; kb < 4; ++kb)
      qf[i][kb] = *(const short8*)(Q + qk0 + (size_t)(q0 + 16 * i + lr) * DH +
                                   kb * 32 + lg * 8);

  floatx4 o[2][9];  // jd==8 is the l-column (P . ones)
#pragma unroll
  for (int i = 0; i < 2; ++i)
#pragma unroll
    for (int jd = 0; jd < 9; ++jd) {
      floatx4 z = {0.f, 0.f, 0.f, 0.f};
      o[i][jd] = z;
    }
  float mrun[2] = {-1e38f, -1e38f};

  const short8 onesv = {16256, 16256, 16256, 16256,
                        16256, 16256, 16256, 16256};  // bf16 1.0 x8

  u16* myP = &Ps[wave * 32 * 72];
  const int nkt = 2 * qt + 2;

  // prologue: stage K(0) into Ks[0]
#pragma unroll
  for (int p = 0; p < 4; ++p) {
    const int s = p * 256 + tid;
    const int row = s >> 4, c = s & 15;
    const int g = c ^ (row & 15);
    async_load16(K + qk0 + (size_t)row * DH + g * 8,
                 &Ks[0][(p * 256 + wave * 64) * 8]);
  }
  __syncthreads();

  for (int kt = 0; kt < nkt; ++kt) {
    const int cur = kt & 1, nb = cur ^ 1;
    const int kn = (kt + 1 < nkt) ? kt + 1 : kt;  // clamp last prefetch
    // issue V(kt) stage: 128 rows x 8 chunks, physical chunk = c ^ (row&7)
#pragma unroll
    for (int p = 0; p < 4; ++p) {
      const int s = p * 256 + tid;
      const int row = s >> 3, c = s & 7;
      const int g = c ^ (row & 7);
      async_load16(Vt + (size_t)bh * DH * SEQ + (size_t)row * SEQ + kt * 64 + g * 8,
                   &Vts[(p * 256 + wave * 64) * 8]);
    }
    // issue K(kt+1) stage into the other buffer
#pragma unroll
    for (int p = 0; p < 4; ++p) {
      const int s = p * 256 + tid;
      const int row = s >> 4, c = s & 15;
      const int g = c ^ (row & 15);
      async_load16(K + qk0 + (size_t)(kn * 64 + row) * DH + g * 8,
                   &Ks[nb][(p * 256 + wave * 64) * 8]);
    }

    // S^T = K Q^T strip (swapped operands): lane holds q = q0+16i+lr,
    // kpos = kt*64 + 16j + 4lg + r
    floatx4 st[4][2];
#pragma unroll
    for (int j = 0; j < 4; ++j)
#pragma unroll
      for (int i = 0; i < 2; ++i) {
        floatx4 z = {0.f, 0.f, 0.f, 0.f};
        st[j][i] = z;
      }
#pragma unroll
    for (int kb = 0; kb < 4; ++kb) {
      short8 kf[4];
#pragma unroll
      for (int j = 0; j < 4; ++j)
        kf[j] = *(const short8*)&Ks[cur][(16 * j + lr) * 128 +
                                         (((kb * 4 + lg) ^ lr)) * 8];
      __builtin_amdgcn_s_setprio(1);
#pragma unroll
      for (int j = 0; j < 4; ++j)
#pragma unroll
        for (int i = 0; i < 2; ++i)
          st[j][i] = __builtin_amdgcn_mfma_f32_16x16x32_bf16(kf[j], qf[i][kb],
                                                             st[j][i], 0, 0, 0);
      __builtin_amdgcn_s_setprio(0);
    }

    // causal mask on raw scores (diagonal tiles only)
    if (kt >= 2 * qt) {
#pragma unroll
      for (int j = 0; j < 4; ++j)
#pragma unroll
        for (int i = 0; i < 2; ++i)
#pragma unroll
          for (int r = 0; r < 4; ++r) {
            const int kpos = kt * 64 + 16 * j + 4 * lg + r;
            const int qpos = q0 + 16 * i + lr;
            if (kpos > qpos) st[j][i][r] = -1e30f;
          }
    }

    // row max: 15 in-register fmax + 2 cross-group shfl_xor per i
    float mx[2];
#pragma unroll
    for (int i = 0; i < 2; ++i) {
      float m0v = fmaxf(fmaxf(st[0][i][0], st[0][i][1]),
                        fmaxf(st[0][i][2], st[0][i][3]));
      float m1v = fmaxf(fmaxf(st[1][i][0], st[1][i][1]),
                        fmaxf(st[1][i][2], st[1][i][3]));
      float m2v = fmaxf(fmaxf(st[2][i][0], st[2][i][1]),
                        fmaxf(st[2][i][2], st[2][i][3]));
      float m3v = fmaxf(fmaxf(st[3][i][0], st[3][i][1]),
                        fmaxf(st[3][i][2], st[3][i][3]));
      float m = fmaxf(fmaxf(m0v, m1v), fmaxf(m2v, m3v));
      m = fmaxf(m, __shfl_xor(m, 16));
      m = fmaxf(m, __shfl_xor(m, 32));
      mx[i] = m;
    }
    const float grow = fmaxf(mx[0] - mrun[0], mx[1] - mrun[1]);
    if (!__all(grow <= RTHR)) {
      float aS[2];
#pragma unroll
      for (int i = 0; i < 2; ++i) {
        const float mn = fmaxf(mrun[i], mx[i]);
        aS[i] = exp2f((mrun[i] - mn) * C);
        mrun[i] = mn;
      }
      // redistribute alpha from S-layout (q=16i+lr) to O-layout (q=16i+4lg+r)
#pragma unroll
      for (int i = 0; i < 2; ++i)
#pragma unroll
        for (int r = 0; r < 4; ++r) {
          const float aO = __shfl(aS[i], 4 * lg + r);
#pragma unroll
          for (int jd = 0; jd < 9; ++jd) o[i][jd][r] *= aO;
        }
    }
    float negMC[2];
#pragma unroll
    for (int i = 0; i < 2; ++i) negMC[i] = -mrun[i] * C;

    // P = exp2(s*C - m*C); pack 4 bf16 per (i,j) and write one b64
#pragma unroll
    for (int i = 0; i < 2; ++i)
#pragma unroll
      for (int j = 0; j < 4; ++j) {
        const float p0 = exp2f(fmaf(st[j][i][0], C, negMC[i]));
        const float p1 = exp2f(fmaf(st[j][i][1], C, negMC[i]));
        const float p2 = exp2f(fmaf(st[j][i][2], C, negMC[i]));
        const float p3 = exp2f(fmaf(st[j][i][3], C, negMC[i]));
        uint2v w;
        w[0] = (u32)f2bf(p0) | ((u32)f2bf(p1) << 16);
        w[1] = (u32)f2bf(p2) | ((u32)f2bf(p3) << 16);
        *(uint2v*)&myP[(16 * i + lr) * 72 + 16 * j + 4 * lg] = w;
      }

    // drain our ds_writes of P before reading them back as A-fragments
    asm volatile("s_waitcnt lgkmcnt(0)" ::: "memory");
    __syncthreads();  // drains vmcnt: V(kt) and K(kt+1) have landed

#pragma unroll
    for (int kb = 0; kb < 2; ++kb) {
      short8 pf[2];
#pragma unroll
      for (int i = 0; i < 2; ++i)
        pf[i] = *(const short8*)&myP[(16 * i + lr) * 72 + kb * 32 + lg * 8];
      __builtin_amdgcn_s_setprio(1);
#pragma unroll
      for (int jd = 0; jd < 8; ++jd) {
        const short8 vf = *(const short8*)&Vts[(16 * jd + lr) * 64 +
                                               (((kb * 4 + lg) ^ (lr & 7))) * 8];
#pragma unroll
        for (int i = 0; i < 2; ++i)
          o[i][jd] = __builtin_amdgcn_mfma_f32_16x16x32_bf16(pf[i], vf, o[i][jd],
                                                             0, 0, 0);
      }
      // l-column: row sums of P via MFMA with an all-ones B fragment
#pragma unroll
      for (int i = 0; i < 2; ++i)
        o[i][8] = __builtin_amdgcn_mfma_f32_16x16x32_bf16(pf[i], onesv, o[i][8],
                                                          0, 0, 0);
      __builtin_amdgcn_s_setprio(0);
    }
    __syncthreads();  // all waves done with Vts / Ks[cur] before next overwrite
  }

  const int b = bh >> 4, h = bh & (NH - 1);
#pragma unroll
  for (int i = 0; i < 2; ++i)
#pragma unroll
    for (int r = 0; r < 4; ++r) {
      const int qpos = q0 + 16 * i + lg * 4 + r;
      const float inv = 1.0f / o[i][8][r];
      u16* dst = Oflat + ((size_t)(b * SEQ + qpos)) * D_MODEL + h * DH;
#pragma unroll
      for (int jd = 0; jd < 8; ++jd) dst[16 * jd + lr] = f2bf(o[i][jd][r] * inv);
    }
}

// ---------------------------------------------------------------------------
// Round-1 fallback GEMM (f32 sources) — used only if ws too small.
// ---------------------------------------------------------------------------
template <int ABF16>
__global__ __launch_bounds__(256, 2) void gemm_kernel(
    const void* __restrict__ Aptr, const float* __restrict__ W,
    const float* __restrict__ bias, void* __restrict__ Cptr, const int mode) {
  __shared__ u16 As[128 * 72];
  __shared__ u16 Bs[128 * 72];
  const int tid = threadIdx.x;
  const int wave = tid >> 6, lane = tid & 63;
  const int lr = lane & 15, lg = lane >> 4;
  const int m0 = blockIdx.y * 128, n0 = blockIdx.x * 128;
  const int wm = (wave & 1) * 64, wn = (wave >> 1) * 64;

  floatx4 acc[4][4];
#pragma unroll
  for (int i = 0; i < 4; ++i)
#pragma unroll
    for (int j = 0; j < 4; ++j) {
      floatx4 z = {0.f, 0.f, 0.f, 0.f};
      acc[i][j] = z;
    }

  for (int kt = 0; kt < D_MODEL; kt += 64) {
    if (ABF16) {
      const u16* A = (const u16*)Aptr;
      const int row0 = tid >> 3, c8 = (tid & 7) * 8;
#pragma unroll
      for (int p = 0; p < 4; ++p) {
        const int row = row0 + p * 32;
        *(short8*)&As[row * 72 + c8] =
            *(const short8*)(A + (size_t)(m0 + row) * D_MODEL + kt + c8);
      }
    } else {
      const float* A = (const float*)Aptr;
      const int row0 = tid >> 4, c4 = (tid & 15) * 4;
#pragma unroll
      for (int p = 0; p < 8; ++p) {
        const int row = row0 + p * 16;
        const floatx4 v =
            *(const floatx4*)(A + (size_t)(m0 + row) * D_MODEL + kt + c4);
        ushort4v h;
        h[0] = f2bf(v[0]); h[1] = f2bf(v[1]); h[2] = f2bf(v[2]); h[3] = f2bf(v[3]);
        *(ushort4v*)&As[row * 72 + c4] = h;
      }
    }
    {
      const int row0 = tid >> 4, c4 = (tid & 15) * 4;
#pragma unroll
      for (int p = 0; p < 8; ++p) {
        const int row = row0 + p * 16;
        const floatx4 v =
            *(const floatx4*)(W + (size_t)(n0 + row) * D_MODEL + kt + c4);
        ushort4v h;
        h[0] = f2bf(v[0]); h[1] = f2bf(v[1]); h[2] = f2bf(v[2]); h[3] = f2bf(v[3]);
        *(ushort4v*)&Bs[row * 72 + c4] = h;
      }
    }
    __syncthreads();
#pragma unroll
    for (int ks = 0; ks < 2; ++ks) {
      short8 af[4], bfr[4];
#pragma unroll
      for (int i = 0; i < 4; ++i)
        af[i] = *(const short8*)&As[(wm + 16 * i + lr) * 72 + ks * 32 + lg * 8];
#pragma unroll
      for (int j = 0; j < 4; ++j)
        bfr[j] = *(const short8*)&Bs[(wn + 16 * j + lr) * 72 + ks * 32 + lg * 8];
#pragma unroll
      for (int i = 0; i < 4; ++i)
#pragma unroll
        for (int j = 0; j < 4; ++j)
          acc[i][j] = __builtin_amdgcn_mfma_f32_16x16x32_bf16(af[i], bfr[j],
                                                              acc[i][j], 0, 0, 0);
    }
    __syncthreads();
  }

  float bj[4];
  int ncol[4];
#pragma unroll
  for (int j = 0; j < 4; ++j) {
    ncol[j] = n0 + wn + 16 * j + lr;
    bj[j] = bias[ncol[j]];
  }

  if (mode == 3) {
    float* C = (float*)Cptr;
#pragma unroll
    for (int i = 0; i < 4; ++i)
#pragma unroll
      for (int r = 0; r < 4; ++r) {
        const int m = m0 + wm + 16 * i + lg * 4 + r;
#pragma unroll
        for (int j = 0; j < 4; ++j)
          C[(size_t)m * D_MODEL + ncol[j]] = acc[i][j][r] + bj[j];
      }
  } else if (mode == 2) {
    u16* C = (u16*)Cptr;
#pragma unroll
    for (int i = 0; i < 4; ++i)
#pragma unroll
      for (int r = 0; r < 4; ++r) {
        const int m = m0 + wm + 16 * i + lg * 4 + r;
        const int b = m >> 11, s = m & (SEQ - 1);
#pragma unroll
        for (int j = 0; j < 4; ++j) {
          const int h = ncol[j] >> 7, d = ncol[j] & (DH - 1);
          C[((size_t)((b * NH + h) * DH + d)) * SEQ + s] = f2bf(acc[i][j][r] + bj[j]);
        }
      }
  } else {
    u16* C = (u16*)Cptr;
#pragma unroll
    for (int i = 0; i < 4; ++i)
#pragma unroll
      for (int r = 0; r < 4; ++r) {
        const int m = m0 + wm + 16 * i + lg * 4 + r;
        const int b = m >> 11, s = m & (SEQ - 1);
#pragma unroll
        for (int j = 0; j < 4; ++j) {
          const int h = ncol[j] >> 7, d = ncol[j] & (DH - 1);
          C[((size_t)((b * NH + h) * SEQ + s)) * DH + d] = f2bf(acc[i][j][r] + bj[j]);
        }
      }
  }
}

// ---------------------------------------------------------------------------
extern "C" void kernel_launch(void* const* d_in, const int* in_sizes, int n_in,
                              void* d_out, int out_size, void* d_ws,
                              size_t ws_size, hipStream_t stream) {
  const float* x = (const float*)d_in[0];
  const float* Wq = (const float*)d_in[1];
  const float* bq = (const float*)d_in[2];
  const float* Wk = (const float*)d_in[3];
  const float* bk = (const float*)d_in[4];
  const float* Wv = (const float*)d_in[5];
  const float* bv = (const float*)d_in[6];
  const float* Wo = (const float*)d_in[7];
  const float* bo = (const float*)d_in[8];
  float* out = (float*)d_out;

  const size_t E = (size_t)NBH * SEQ * DH;
  const size_t WE = (size_t)D_MODEL * D_MODEL;
  const size_t need = (4 * E + 3 * WE) * sizeof(u16);  // 92.3 MB

  const dim3 gb(256);

  if (ws_size >= need) {
    u16* xb = (u16*)d_ws;
    u16* wqb = xb + E;
    u16* wkb = wqb + WE;
    u16* wvb = wkb + WE;
    u16* q = wvb + WE;
    u16* k = q + E;
    u16* vt = k + E;
    u16* aflat = xb;   // xb dead after QKV GEMM
    u16* wob = q;      // q dead after attention
    // RoPE table scratch lives in d_out (dead until the final GEMM, which
    // overwrites all of it). 512 KB = SEQ*64 packed half2.
    u32* rtab = (u32*)out;

    cvt4_kernel<<<dim3(10368), gb, 0, stream>>>(x, Wq, Wk, Wv, xb, wqb, wkb,
                                                wvb, rtab);

    gemm_async<<<dim3(48, 32), gb, 0, stream>>>(xb, wqb, wkb, wvb, bq, bk, bv,
                                                q, k, vt, rtab, 1);
    attn_kernel<<<dim3(SEQ / 128, NBH), gb, 0, stream>>>(q, k, vt, aflat);
    cvt_kernel<<<dim3((int)(WE / 2048)), gb, 0, stream>>>(Wo, wob, (int)WE);
    gemm_async<<<dim3(16, 32), gb, 0, stream>>>(aflat, wob, nullptr, nullptr,
                                                bo, nullptr, nullptr, out,
                                                nullptr, nullptr, nullptr, 0);
  } else {
    u16* q = (u16*)d_ws;
    u16* k = q + E;
    u16* vt = k + E;
    u16* aflat = vt + E;
    const dim3 gg(D_MODEL / 128, (2 * SEQ) / 128);
    gemm_kernel<0><<<gg, gb, 0, stream>>>(x, Wq, bq, q, 0);
    gemm_kernel<0><<<gg, gb, 0, stream>>>(x, Wk, bk, k, 1);
    gemm_kernel<0><<<gg, gb, 0, stream>>>(x, Wv, bv, vt, 2);
    rope_kernel<<<dim3((NBH * SEQ * (DH / 2)) / 256), dim3(256), 0, stream>>>(q, k);
    attn_kernel<<<dim3(SEQ / 128, NBH), gb, 0, stream>>>(q, k, vt, aflat);
    gemm_kernel<1><<<gg, gb, 0, stream>>>(aflat, Wo, bo, out, 3);
  }
}